// Round 1
// baseline (434.394 us; speedup 1.0000x reference)
//
#include <hip/hip_runtime.h>

#define Bc 16
#define Hc 8
#define Lc 4096
#define Ec 64
#define Mc 64
#define BHc (Bc*Hc)

// ---------------------------------------------------------------------------
// Twiddle tables: cos/sin(2*pi*k_m*l/L) in both [l][m] and [m][l] layouts.
// ---------------------------------------------------------------------------
__global__ void twiddle_k(const int* __restrict__ idx,
                          float* __restrict__ cosLM, float* __restrict__ sinLM,
                          float* __restrict__ cosML, float* __restrict__ sinML) {
    int t = blockIdx.x * 256 + threadIdx.x;   // t = l*Mc + m
    int l = t >> 6;
    int m = t & 63;
    int k = idx[m];
    int ph = (k * l) & (Lc - 1);              // (k*l) mod 4096
    float ang = (float)ph * 1.5339807878856412e-3f;  // * 2*pi/4096
    float s, c;
    sincosf(ang, &s, &c);
    cosLM[t] = c;
    sinLM[t] = s;
    cosML[m * Lc + l] = c;
    sinML[m * Lc + l] = s;
}

// ---------------------------------------------------------------------------
// Forward: partial DFT over an L-chunk.  sel_partial[ch][bh][e][m][2]
// grid (BHc, nch), block 128.  Thread owns 4 e x 8 m accumulators.
// ---------------------------------------------------------------------------
__global__ void fwd_k(const float* __restrict__ x,
                      const float* __restrict__ cosLM, const float* __restrict__ sinLM,
                      float* __restrict__ selP, int nch) {
    const int TL = 32;
    __shared__ float xs[TL * Ec];   // 8KB
    __shared__ float cs[TL * Mc];   // 8KB
    __shared__ float sn[TL * Mc];   // 8KB
    int bh = blockIdx.x;
    int ch = blockIdx.y;
    int chunk = Lc / nch;
    int tid = threadIdx.x;
    int e0 = (tid & 15) * 4;
    int m0 = (tid >> 4) * 8;
    float aR[4][8] = {{0}}, aI[4][8] = {{0}};
    const float* xp = x + (size_t)bh * Lc * Ec;
    for (int t0 = ch * chunk; t0 < (ch + 1) * chunk; t0 += TL) {
        const float4* gx = (const float4*)(xp + (size_t)t0 * Ec);
        const float4* gc = (const float4*)(cosLM + (size_t)t0 * Mc);
        const float4* gs = (const float4*)(sinLM + (size_t)t0 * Mc);
        #pragma unroll
        for (int i = 0; i < 4; i++) {
            int f4 = i * 128 + tid;
            ((float4*)xs)[f4] = gx[f4];
            ((float4*)cs)[f4] = gc[f4];
            ((float4*)sn)[f4] = gs[f4];
        }
        __syncthreads();
        for (int l = 0; l < TL; l++) {
            float4 xv = *(const float4*)&xs[l * Ec + e0];
            float4 c0 = *(const float4*)&cs[l * Mc + m0];
            float4 c1 = *(const float4*)&cs[l * Mc + m0 + 4];
            float4 s0 = *(const float4*)&sn[l * Mc + m0];
            float4 s1 = *(const float4*)&sn[l * Mc + m0 + 4];
            float xr[4] = {xv.x, xv.y, xv.z, xv.w};
            float cr[8] = {c0.x, c0.y, c0.z, c0.w, c1.x, c1.y, c1.z, c1.w};
            float sr[8] = {s0.x, s0.y, s0.z, s0.w, s1.x, s1.y, s1.z, s1.w};
            #pragma unroll
            for (int i = 0; i < 4; i++) {
                #pragma unroll
                for (int j = 0; j < 8; j++) {
                    aR[i][j] = fmaf(xr[i], cr[j], aR[i][j]);
                    aI[i][j] = fmaf(-xr[i], sr[j], aI[i][j]);
                }
            }
        }
        __syncthreads();
    }
    float* op = selP + ((size_t)(ch * BHc + bh)) * (Ec * Mc * 2);
    #pragma unroll
    for (int i = 0; i < 4; i++) {
        float* rp = op + (e0 + i) * (Mc * 2) + m0 * 2;
        #pragma unroll
        for (int j = 0; j < 8; j += 2) {
            float4 v = make_float4(aR[i][j], aI[i][j], aR[i][j+1], aI[i][j+1]);
            *(float4*)(rp + 2 * j) = v;
        }
    }
}

// ---------------------------------------------------------------------------
// Mix: reduce partials, apply weights einsum, fold irfft scale.
// osel[bh][m][o][2].  grid BHc, block 256.  Thread owns 4 o x 4 m.
// ---------------------------------------------------------------------------
__global__ void mix_k(const float* __restrict__ selP, const float* __restrict__ w,
                      const int* __restrict__ idx, float* __restrict__ osel, int nch) {
    __shared__ float sel_s[Ec * Mc * 2];  // [e][m][2] 32KB
    int bh = blockIdx.x;
    int tid = threadIdx.x;
    #pragma unroll
    for (int i = 0; i < 32; i++) {
        int f = i * 256 + tid;
        float acc = 0.f;
        for (int ch = 0; ch < nch; ch++)
            acc += selP[((size_t)(ch * BHc + bh)) * (Ec * Mc * 2) + f];
        sel_s[f] = acc;
    }
    __syncthreads();
    int o0 = (tid & 15) * 4;
    int m0 = (tid >> 4) * 4;
    float oR[4][4] = {{0}}, oI[4][4] = {{0}};
    for (int e = 0; e < Ec; e++) {
        float4 sa = *(const float4*)&sel_s[e * (Mc * 2) + m0 * 2];
        float4 sb = *(const float4*)&sel_s[e * (Mc * 2) + m0 * 2 + 4];
        float srj[4] = {sa.x, sa.z, sb.x, sb.z};
        float sij[4] = {sa.y, sa.w, sb.y, sb.w};
        #pragma unroll
        for (int i = 0; i < 4; i++) {
            const float4* wp = (const float4*)&w[(((size_t)e * Ec + (o0 + i)) * Mc + m0) * 2];
            float4 wa = wp[0], wb = wp[1];
            float wrj[4] = {wa.x, wa.z, wb.x, wb.z};
            float wij[4] = {wa.y, wa.w, wb.y, wb.w};
            #pragma unroll
            for (int j = 0; j < 4; j++) {
                oR[i][j] += srj[j] * wrj[j] - sij[j] * wij[j];
                oI[i][j] += srj[j] * wij[j] + sij[j] * wrj[j];
            }
        }
    }
    #pragma unroll
    for (int j = 0; j < 4; j++) {
        int m = m0 + j;
        float sc = (idx[m] == 0 ? 1.0f : 2.0f) / (float)Lc;
        float* pp = osel + ((size_t)bh * Mc + m) * (Ec * 2) + o0 * 2;
        #pragma unroll
        for (int i = 0; i < 4; i += 2) {
            float4 v = make_float4(oR[i][j] * sc, oI[i][j] * sc,
                                   oR[i+1][j] * sc, oI[i+1][j] * sc);
            *(float4*)(pp + 2 * i) = v;
        }
    }
}

// ---------------------------------------------------------------------------
// Inverse: out[bh][l][o] = sum_m Re'[m][o]*cos - Im'[m][o]*sin
// grid (BHc, Lc/128), block 256.  Thread owns 4 l x 8 o.
// ---------------------------------------------------------------------------
__global__ void inv_k(const float* __restrict__ osel,
                      const float* __restrict__ cosML, const float* __restrict__ sinML,
                      float* __restrict__ out) {
    __shared__ float os_s[Mc * Ec * 2];  // [m][o][2] 32KB
    __shared__ float cs[16 * 128];       // 8KB
    __shared__ float sn[16 * 128];       // 8KB
    int bh = blockIdx.x;
    int l0 = blockIdx.y * 128;
    int tid = threadIdx.x;
    const float4* go = (const float4*)(osel + (size_t)bh * Mc * Ec * 2);
    #pragma unroll
    for (int i = 0; i < 8; i++)
        ((float4*)os_s)[i * 256 + tid] = go[i * 256 + tid];
    int og = tid & 7;    // 8 groups x 8 o
    int lg = tid >> 3;   // 32 groups x 4 l
    float acc[4][8] = {{0}};
    for (int mh = 0; mh < 4; mh++) {
        __syncthreads();
        #pragma unroll
        for (int i = 0; i < 2; i++) {
            int f4 = i * 256 + tid;          // 512 float4 = 16 rows * 32
            int r = f4 >> 5, c = f4 & 31;
            ((float4*)cs)[f4] = *(const float4*)&cosML[(size_t)(mh * 16 + r) * Lc + l0 + c * 4];
            ((float4*)sn)[f4] = *(const float4*)&sinML[(size_t)(mh * 16 + r) * Lc + l0 + c * 4];
        }
        __syncthreads();
        for (int m = 0; m < 16; m++) {
            float4 c4 = *(const float4*)&cs[m * 128 + lg * 4];
            float4 s4 = *(const float4*)&sn[m * 128 + lg * 4];
            float cv[4] = {c4.x, c4.y, c4.z, c4.w};
            float sv[4] = {s4.x, s4.y, s4.z, s4.w};
            const float* orow = &os_s[(mh * 16 + m) * (Ec * 2) + og * 16];
            float4 p0 = *(const float4*)(orow);
            float4 p1 = *(const float4*)(orow + 4);
            float4 p2 = *(const float4*)(orow + 8);
            float4 p3 = *(const float4*)(orow + 12);
            float re[8] = {p0.x, p0.z, p1.x, p1.z, p2.x, p2.z, p3.x, p3.z};
            float im[8] = {p0.y, p0.w, p1.y, p1.w, p2.y, p2.w, p3.y, p3.w};
            #pragma unroll
            for (int i = 0; i < 4; i++) {
                #pragma unroll
                for (int j = 0; j < 8; j++)
                    acc[i][j] = fmaf(re[j], cv[i], fmaf(-im[j], sv[i], acc[i][j]));
            }
        }
    }
    #pragma unroll
    for (int i = 0; i < 4; i++) {
        int l = l0 + lg * 4 + i;
        float* po = out + ((size_t)bh * Lc + l) * Ec + og * 8;
        *(float4*)po = make_float4(acc[i][0], acc[i][1], acc[i][2], acc[i][3]);
        *(float4*)(po + 4) = make_float4(acc[i][4], acc[i][5], acc[i][6], acc[i][7]);
    }
}

// ---------------------------------------------------------------------------
extern "C" void kernel_launch(void* const* d_in, const int* in_sizes, int n_in,
                              void* d_out, int out_size, void* d_ws, size_t ws_size,
                              hipStream_t stream) {
    const float* x   = (const float*)d_in[0];
    const float* w   = (const float*)d_in[1];
    const int*   idx = (const int*)d_in[2];
    float* out = (float*)d_out;
    float* ws  = (float*)d_ws;

    float* cosLM = ws;
    float* sinLM = cosLM + (size_t)Lc * Mc;
    float* cosML = sinLM + (size_t)Lc * Mc;
    float* sinML = cosML + (size_t)Lc * Mc;
    float* selP  = sinML + (size_t)Lc * Mc;

    // pick number of L-chunks for the forward partials to fit the workspace
    size_t fixed_f = 4ull * Lc * Mc + (size_t)BHc * Mc * Ec * 2;
    int nch = 8;
    while (nch > 1 && (fixed_f + (size_t)nch * BHc * Ec * Mc * 2) * 4 > ws_size) nch >>= 1;
    float* osel = selP + (size_t)nch * BHc * Ec * Mc * 2;

    twiddle_k<<<(Lc * Mc) / 256, 256, 0, stream>>>(idx, cosLM, sinLM, cosML, sinML);
    fwd_k<<<dim3(BHc, nch), 128, 0, stream>>>(x, cosLM, sinLM, selP, nch);
    mix_k<<<BHc, 256, 0, stream>>>(selP, w, idx, osel, nch);
    inv_k<<<dim3(BHc, Lc / 128), 256, 0, stream>>>(osel, cosML, sinML, out);
}

// Round 2
// 131.535 us; speedup vs baseline: 3.3025x; 3.3025x over previous
//
#include <hip/hip_runtime.h>

using half8 = __attribute__((ext_vector_type(8))) _Float16;
using f32x4 = __attribute__((ext_vector_type(4))) float;

#define Lc 4096
#define Ec 64
#define Mc 64
#define BHc 128
#define NCH 4
#define CHUNK (Lc / NCH)

// 2*pi/4096
#define TWO_PI_OVER_L 1.5339807878856412e-3f

// ---------------------------------------------------------------------------
// Twiddle tables, both coalesced:
//   Tt[m2][l]  f16, m2 in [0,128): rows 0..63 = cos(th), rows 64..127 = -sin(th)
//   UL[l][m2]  f16: cols 0..63 = cos(th), cols 64..127 = +sin(th)
// th = 2*pi*k_m*l/L
// ---------------------------------------------------------------------------
__global__ __launch_bounds__(256) void twid_k(const int* __restrict__ idx,
                                              _Float16* __restrict__ Tt,
                                              _Float16* __restrict__ UL) {
    int id = blockIdx.x * 256 + threadIdx.x;   // 0 .. 524287
    {   // UL pass: l = id>>7, m2 = id&127  (coalesced in m2)
        int l = id >> 7, m2 = id & 127, m = m2 & 63;
        int k = idx[m];
        int ph = (k * l) & (Lc - 1);
        float s, c;
        sincosf((float)ph * TWO_PI_OVER_L, &s, &c);
        UL[id] = (_Float16)((m2 >= 64) ? s : c);
    }
    {   // Tt pass: m2 = id>>12, l = id&4095  (coalesced in l)
        int m2 = id >> 12, l = id & 4095, m = m2 & 63;
        int k = idx[m];
        int ph = (k * l) & (Lc - 1);
        float s, c;
        sincosf((float)ph * TWO_PI_OVER_L, &s, &c);
        Tt[id] = (_Float16)((m2 >= 64) ? -s : c);
    }
}

// ---------------------------------------------------------------------------
// Forward: selP[ch][bh][m2=128][e=64] = sum_{l in chunk} Tt[m2][l] * x[bh][l][e]
// grid (BHc, NCH), 256 thr (4 waves). Wave w owns m2 rows [32w, 32w+32).
// mfma_f32_16x16x32_f16: A row=lane&15, k=(lane>>4)*8+i; B col=lane&15, same k;
// D col=lane&15, row=(lane>>4)*4+reg.
// ---------------------------------------------------------------------------
__global__ __launch_bounds__(256) void fwd_k(const float* __restrict__ x,
                                             const _Float16* __restrict__ Tt,
                                             float* __restrict__ selP) {
    __shared__ _Float16 xs[Ec * 48];           // [e][48] f16, 6KB
    int bh = blockIdx.x, ch = blockIdx.y;
    int tid = threadIdx.x;
    int lane = tid & 63, w = tid >> 6;
    int eg = tid & 15, lp = tid >> 4;          // staging map
    int lo16 = lane & 15, kg = lane >> 4;
    const float* xp = x + ((size_t)bh * Lc + (size_t)ch * CHUNK) * Ec;
    const _Float16* tp = Tt + (size_t)(w * 32 + lo16) * Lc + ch * CHUNK + kg * 8;
    f32x4 acc[2][4] = {};
    for (int s = 0; s < CHUNK / 32; ++s) {
        const float* gl = xp + (size_t)(s * 32 + 2 * lp) * Ec + eg * 4;
        float4 xa = *(const float4*)gl;
        float4 xb = *(const float4*)(gl + Ec);
        __syncthreads();                       // prior reads of xs done
        {
            const float* pa = &xa.x;
            const float* pb = &xb.x;
            #pragma unroll
            for (int i = 0; i < 4; ++i) {
                unsigned short ua = __builtin_bit_cast(unsigned short, (_Float16)pa[i]);
                unsigned short ub = __builtin_bit_cast(unsigned short, (_Float16)pb[i]);
                unsigned int pk = ua | ((unsigned int)ub << 16);
                *(unsigned int*)&xs[(eg * 4 + i) * 48 + 2 * lp] = pk;
            }
        }
        __syncthreads();
        half8 A0 = *(const half8*)(tp + s * 32);
        half8 A1 = *(const half8*)(tp + 16 * Lc + s * 32);
        #pragma unroll
        for (int j = 0; j < 4; ++j) {
            half8 B = *(const half8*)&xs[(16 * j + lo16) * 48 + kg * 8];
            acc[0][j] = __builtin_amdgcn_mfma_f32_16x16x32_f16(A0, B, acc[0][j], 0, 0, 0);
            acc[1][j] = __builtin_amdgcn_mfma_f32_16x16x32_f16(A1, B, acc[1][j], 0, 0, 0);
        }
    }
    float* op = selP + (size_t)(ch * BHc + bh) * (128 * Ec);
    #pragma unroll
    for (int a = 0; a < 2; ++a)
        #pragma unroll
        for (int j = 0; j < 4; ++j)
            #pragma unroll
            for (int r = 0; r < 4; ++r) {
                int m2 = w * 32 + a * 16 + kg * 4 + r;
                int e  = 16 * j + lo16;
                op[m2 * Ec + e] = acc[a][j][r];
            }
}

// ---------------------------------------------------------------------------
// Mix: reduce K-partials, apply complex weight einsum, fold irfft scale.
// Vt[bh][o=64][m2=128] f16: cols 0..63 = s*Re(out_sel), 64..127 = -s*Im(out_sel)
// grid (BHc, 2) o-halves, 256 thr. Thread owns 4 o x 2 m.
// ---------------------------------------------------------------------------
__global__ __launch_bounds__(256) void mix_k(const float* __restrict__ selP,
                                             const float* __restrict__ wgt,
                                             const int* __restrict__ idx,
                                             _Float16* __restrict__ Vt) {
    __shared__ float sel_s[128 * 65];          // [m2][65] padded, 33.3KB
    int bh = blockIdx.x, oh = blockIdx.y;
    int tid = threadIdx.x;
    #pragma unroll
    for (int i = 0; i < 8; ++i) {
        int f4 = i * 256 + tid;                // 2048 float4 = 8192 floats
        const float4* p0 = (const float4*)(selP + (size_t)(0 * BHc + bh) * 8192) + f4;
        const float4* p1 = (const float4*)(selP + (size_t)(1 * BHc + bh) * 8192) + f4;
        const float4* p2 = (const float4*)(selP + (size_t)(2 * BHc + bh) * 8192) + f4;
        const float4* p3 = (const float4*)(selP + (size_t)(3 * BHc + bh) * 8192) + f4;
        float4 a = *p0, b = *p1, c = *p2, d = *p3;
        int m2 = f4 >> 4, e4 = (f4 & 15) * 4;
        float* dst = &sel_s[m2 * 65 + e4];
        dst[0] = a.x + b.x + c.x + d.x;
        dst[1] = a.y + b.y + c.y + d.y;
        dst[2] = a.z + b.z + c.z + d.z;
        dst[3] = a.w + b.w + c.w + d.w;
    }
    __syncthreads();
    int og = tid & 7, mg = tid >> 3;
    int o0 = oh * 32 + og * 4;
    int m0 = mg * 2;
    float rR[4][2] = {{0}}, rI[4][2] = {{0}};
    for (int e = 0; e < Ec; ++e) {
        float sr0 = sel_s[m0 * 65 + e];
        float sr1 = sel_s[(m0 + 1) * 65 + e];
        float si0 = sel_s[(64 + m0) * 65 + e];
        float si1 = sel_s[(64 + m0 + 1) * 65 + e];
        #pragma unroll
        for (int i = 0; i < 4; ++i) {
            const float4* wp = (const float4*)&wgt[(((size_t)e * Ec + (o0 + i)) * Mc + m0) * 2];
            float4 wv = *wp;   // wR[m0], wI[m0], wR[m0+1], wI[m0+1]
            rR[i][0] += sr0 * wv.x - si0 * wv.y;
            rI[i][0] += sr0 * wv.y + si0 * wv.x;
            rR[i][1] += sr1 * wv.z - si1 * wv.w;
            rI[i][1] += sr1 * wv.w + si1 * wv.z;
        }
    }
    float s0 = (idx[m0] == 0 ? 1.0f : 2.0f) / (float)Lc;
    float s1 = (idx[m0 + 1] == 0 ? 1.0f : 2.0f) / (float)Lc;
    #pragma unroll
    for (int i = 0; i < 4; ++i) {
        _Float16* vp = Vt + ((size_t)bh * 64 + o0 + i) * 128;
        unsigned short r0 = __builtin_bit_cast(unsigned short, (_Float16)(rR[i][0] * s0));
        unsigned short r1 = __builtin_bit_cast(unsigned short, (_Float16)(rR[i][1] * s1));
        unsigned short i0 = __builtin_bit_cast(unsigned short, (_Float16)(-rI[i][0] * s0));
        unsigned short i1 = __builtin_bit_cast(unsigned short, (_Float16)(-rI[i][1] * s1));
        *(unsigned int*)&vp[m0]      = r0 | ((unsigned int)r1 << 16);
        *(unsigned int*)&vp[64 + m0] = i0 | ((unsigned int)i1 << 16);
    }
}

// ---------------------------------------------------------------------------
// Inverse: out[bh][l][o] = sum_{m2} UL[l][m2] * V[m2][o]
// grid (BHc, 16), 256 thr. Wave w owns l rows [64w, 64w+64) of a 256-l block.
// Vt staged in LDS [o][136] (17-bank stride -> conflict-free b128 reads).
// ---------------------------------------------------------------------------
__global__ __launch_bounds__(256) void inv_k(const _Float16* __restrict__ UL,
                                             const _Float16* __restrict__ Vt,
                                             float* __restrict__ out) {
    __shared__ _Float16 vs[64 * 136];          // 17.4KB
    int bh = blockIdx.x, lb = blockIdx.y;
    int tid = threadIdx.x, lane = tid & 63, w = tid >> 6;
    int lo16 = lane & 15, kg = lane >> 4;
    #pragma unroll
    for (int i = 0; i < 4; ++i) {
        int f = i * 256 + tid;                 // 1024 chunks of 8 f16
        int row = f >> 4, seg = f & 15;
        uint4 t4 = *(const uint4*)(Vt + (size_t)bh * 8192 + row * 128 + seg * 8);
        *(uint4*)&vs[row * 136 + seg * 8] = t4;
    }
    __syncthreads();
    int lt0 = lb * 256 + w * 64;
    const _Float16* up = UL + (size_t)(lt0 + lo16) * 128 + kg * 8;
    f32x4 acc[4][4] = {};
    #pragma unroll
    for (int ks = 0; ks < 4; ++ks) {
        half8 Af[4];
        #pragma unroll
        for (int a = 0; a < 4; ++a)
            Af[a] = *(const half8*)(up + (size_t)a * 16 * 128 + ks * 32);
        #pragma unroll
        for (int j = 0; j < 4; ++j) {
            half8 Bf = *(const half8*)&vs[(16 * j + lo16) * 136 + ks * 32 + kg * 8];
            #pragma unroll
            for (int a = 0; a < 4; ++a)
                acc[a][j] = __builtin_amdgcn_mfma_f32_16x16x32_f16(Af[a], Bf, acc[a][j], 0, 0, 0);
        }
    }
    float* op = out + ((size_t)bh * Lc + lt0) * Ec;
    #pragma unroll
    for (int a = 0; a < 4; ++a)
        #pragma unroll
        for (int j = 0; j < 4; ++j)
            #pragma unroll
            for (int r = 0; r < 4; ++r) {
                int ll = a * 16 + kg * 4 + r;
                int o  = 16 * j + lo16;
                op[ll * Ec + o] = acc[a][j][r];
            }
}

// ---------------------------------------------------------------------------
extern "C" void kernel_launch(void* const* d_in, const int* in_sizes, int n_in,
                              void* d_out, int out_size, void* d_ws, size_t ws_size,
                              hipStream_t stream) {
    const float* x   = (const float*)d_in[0];
    const float* wgt = (const float*)d_in[1];
    const int*   idx = (const int*)d_in[2];
    float* out = (float*)d_out;

    char* ws = (char*)d_ws;
    float*    selP = (float*)ws;                                   // 16 MB
    _Float16* Tt   = (_Float16*)(ws + (size_t)NCH * BHc * 8192 * 4);
    _Float16* UL   = Tt + (size_t)128 * Lc;                        // 1 MB each
    _Float16* Vt   = UL + (size_t)Lc * 128;                        // 2 MB

    twid_k<<<2048, 256, 0, stream>>>(idx, Tt, UL);
    fwd_k<<<dim3(BHc, NCH), 256, 0, stream>>>(x, Tt, selP);
    mix_k<<<dim3(BHc, 2), 256, 0, stream>>>(selP, wgt, idx, Vt);
    inv_k<<<dim3(BHc, 16), 256, 0, stream>>>(UL, Vt, out);
}

// Round 3
// 129.756 us; speedup vs baseline: 3.3478x; 1.0137x over previous
//
#include <hip/hip_runtime.h>

using half8 = __attribute__((ext_vector_type(8))) _Float16;
using f32x4 = __attribute__((ext_vector_type(4))) float;

#define Lc 4096
#define Ec 64
#define Mc 64
#define BHc 128

// 2*pi/4096
#define TWO_PI_OVER_L 1.5339807878856412e-3f

// ---------------------------------------------------------------------------
// Twiddle tables, both coalesced:
//   Tt[m2][l]  f16, m2 in [0,128): rows 0..63 = cos(th), rows 64..127 = -sin(th)
//   UL[l][m2]  f16: cols 0..63 = cos(th), cols 64..127 = +sin(th)
// th = 2*pi*k_m*l/L
// ---------------------------------------------------------------------------
__global__ __launch_bounds__(256) void twid_k(const int* __restrict__ idx,
                                              _Float16* __restrict__ Tt,
                                              _Float16* __restrict__ UL) {
    int id = blockIdx.x * 256 + threadIdx.x;   // 0 .. 524287
    {   // UL pass: l = id>>7, m2 = id&127  (coalesced in m2)
        int l = id >> 7, m2 = id & 127, m = m2 & 63;
        int k = idx[m];
        int ph = (k * l) & (Lc - 1);
        float s, c;
        sincosf((float)ph * TWO_PI_OVER_L, &s, &c);
        UL[id] = (_Float16)((m2 >= 64) ? s : c);
    }
    {   // Tt pass: m2 = id>>12, l = id&4095  (coalesced in l)
        int m2 = id >> 12, l = id & 4095, m = m2 & 63;
        int k = idx[m];
        int ph = (k * l) & (Lc - 1);
        float s, c;
        sincosf((float)ph * TWO_PI_OVER_L, &s, &c);
        Tt[id] = (_Float16)((m2 >= 64) ? -s : c);
    }
}

// ---------------------------------------------------------------------------
// Forward: selP[ch][bh][m2=128][e=64] = sum_{l in chunk} Tt[m2][l] * x[bh][l][e]
// grid (BHc, NCH), 256 thr (4 waves). Wave w owns m2 rows [32w, 32w+32).
// 64-row tiles, register-prefetch double buffer, XOR-swizzled LDS transpose.
// xs layout: [e][l] f16, row = 128B, byte ^= ((e&7)<<4).
// ---------------------------------------------------------------------------
template<int NCH>
__global__ __launch_bounds__(256) void fwd_k(const float* __restrict__ x,
                                             const _Float16* __restrict__ Tt,
                                             float* __restrict__ selP) {
    constexpr int CH = Lc / NCH;
    constexpr int NT = CH / 64;
    __shared__ _Float16 xs[64 * 64];           // 8KB
    int bh = blockIdx.x, ch = blockIdx.y;
    int tid = threadIdx.x;
    int lane = tid & 63, w = tid >> 6;
    int lo16 = lane & 15, kg = lane >> 4;
    int col4 = tid & 15, lp = tid >> 4;        // staging: e4=col4*4, row-pair lp

    const float* xp = x + ((size_t)bh * Lc + (size_t)ch * CH) * Ec + col4 * 4;
    const _Float16* tp = Tt + (size_t)(w * 32 + lo16) * Lc + ch * CH + kg * 8;

    float4 xa[2], xb[2];
    #pragma unroll
    for (int i = 0; i < 2; ++i) {              // preload tile 0
        const float* g = xp + (size_t)(2 * lp + 32 * i) * Ec;
        xa[i] = *(const float4*)g;
        xb[i] = *(const float4*)(g + Ec);
    }

    f32x4 acc[2][4] = {};
    for (int s = 0; s < NT; ++s) {
        unsigned int pk[2][4];
        #pragma unroll
        for (int i = 0; i < 2; ++i) {
            const float* pa = (const float*)&xa[i];
            const float* pb = (const float*)&xb[i];
            #pragma unroll
            for (int j = 0; j < 4; ++j) {
                unsigned short ua = __builtin_bit_cast(unsigned short, (_Float16)pa[j]);
                unsigned short ub = __builtin_bit_cast(unsigned short, (_Float16)pb[j]);
                pk[i][j] = ua | ((unsigned int)ub << 16);
            }
        }
        __syncthreads();                       // prior tile's reads complete
        #pragma unroll
        for (int i = 0; i < 2; ++i)
            #pragma unroll
            for (int j = 0; j < 4; ++j) {
                int jr = (j + col4) & 3;       // per-lane rotation -> bank spread
                int e = col4 * 4 + jr;
                int byt = (e * 128 + lp * 4 + i * 64) ^ ((e & 7) << 4);
                *(unsigned int*)((char*)xs + byt) = pk[i][jr];
            }
        __syncthreads();
        if (s + 1 < NT) {                      // prefetch next tile (overlaps MFMA)
            #pragma unroll
            for (int i = 0; i < 2; ++i) {
                const float* g = xp + (size_t)((s + 1) * 64 + 2 * lp + 32 * i) * Ec;
                xa[i] = *(const float4*)g;
                xb[i] = *(const float4*)(g + Ec);
            }
        }
        #pragma unroll
        for (int ks = 0; ks < 2; ++ks) {
            half8 A0 = *(const half8*)(tp + s * 64 + ks * 32);
            half8 A1 = *(const half8*)(tp + (size_t)16 * Lc + s * 64 + ks * 32);
            #pragma unroll
            for (int j = 0; j < 4; ++j) {
                int rb = ((16 * j + lo16) * 128 + ks * 64 + kg * 16) ^ ((lo16 & 7) << 4);
                half8 B = *(const half8*)((const char*)xs + rb);
                acc[0][j] = __builtin_amdgcn_mfma_f32_16x16x32_f16(A0, B, acc[0][j], 0, 0, 0);
                acc[1][j] = __builtin_amdgcn_mfma_f32_16x16x32_f16(A1, B, acc[1][j], 0, 0, 0);
            }
        }
    }
    float* op = selP + (size_t)(ch * BHc + bh) * (128 * Ec);
    #pragma unroll
    for (int a = 0; a < 2; ++a)
        #pragma unroll
        for (int j = 0; j < 4; ++j)
            #pragma unroll
            for (int r = 0; r < 4; ++r) {
                int m2 = w * 32 + a * 16 + kg * 4 + r;
                int e  = 16 * j + lo16;
                op[m2 * Ec + e] = acc[a][j][r];
            }
}

// ---------------------------------------------------------------------------
// Mix: reduce K-partials, apply complex weight einsum, fold irfft scale.
// Vt[bh][o=64][m2=128] f16: cols 0..63 = s*Re(out_sel), 64..127 = -s*Im(out_sel)
// grid (BHc, 2) o-halves, 256 thr. Thread owns 4 o x 2 m.
// ---------------------------------------------------------------------------
__global__ __launch_bounds__(256) void mix_k(const float* __restrict__ selP,
                                             const float* __restrict__ wgt,
                                             const int* __restrict__ idx,
                                             _Float16* __restrict__ Vt, int nch) {
    __shared__ float sel_s[128 * 65];          // [m2][65] padded, 33.3KB
    int bh = blockIdx.x, oh = blockIdx.y;
    int tid = threadIdx.x;
    #pragma unroll
    for (int i = 0; i < 8; ++i) {
        int f4 = i * 256 + tid;                // 2048 float4 = 8192 floats
        float4 a = make_float4(0.f, 0.f, 0.f, 0.f);
        for (int chn = 0; chn < nch; ++chn) {
            float4 v = *((const float4*)(selP + (size_t)(chn * BHc + bh) * 8192) + f4);
            a.x += v.x; a.y += v.y; a.z += v.z; a.w += v.w;
        }
        int m2 = f4 >> 4, e4 = (f4 & 15) * 4;
        float* dst = &sel_s[m2 * 65 + e4];
        dst[0] = a.x; dst[1] = a.y; dst[2] = a.z; dst[3] = a.w;
    }
    __syncthreads();
    int og = tid & 7, mg = tid >> 3;
    int o0 = oh * 32 + og * 4;
    int m0 = mg * 2;
    float rR[4][2] = {{0}}, rI[4][2] = {{0}};
    for (int e = 0; e < Ec; ++e) {
        float sr0 = sel_s[m0 * 65 + e];
        float sr1 = sel_s[(m0 + 1) * 65 + e];
        float si0 = sel_s[(64 + m0) * 65 + e];
        float si1 = sel_s[(64 + m0 + 1) * 65 + e];
        #pragma unroll
        for (int i = 0; i < 4; ++i) {
            const float4* wp = (const float4*)&wgt[(((size_t)e * Ec + (o0 + i)) * Mc + m0) * 2];
            float4 wv = *wp;   // wR[m0], wI[m0], wR[m0+1], wI[m0+1]
            rR[i][0] += sr0 * wv.x - si0 * wv.y;
            rI[i][0] += sr0 * wv.y + si0 * wv.x;
            rR[i][1] += sr1 * wv.z - si1 * wv.w;
            rI[i][1] += sr1 * wv.w + si1 * wv.z;
        }
    }
    float s0 = (idx[m0] == 0 ? 1.0f : 2.0f) / (float)Lc;
    float s1 = (idx[m0 + 1] == 0 ? 1.0f : 2.0f) / (float)Lc;
    #pragma unroll
    for (int i = 0; i < 4; ++i) {
        _Float16* vp = Vt + ((size_t)bh * 64 + o0 + i) * 128;
        unsigned short r0 = __builtin_bit_cast(unsigned short, (_Float16)(rR[i][0] * s0));
        unsigned short r1 = __builtin_bit_cast(unsigned short, (_Float16)(rR[i][1] * s1));
        unsigned short i0 = __builtin_bit_cast(unsigned short, (_Float16)(-rI[i][0] * s0));
        unsigned short i1 = __builtin_bit_cast(unsigned short, (_Float16)(-rI[i][1] * s1));
        *(unsigned int*)&vp[m0]      = r0 | ((unsigned int)r1 << 16);
        *(unsigned int*)&vp[64 + m0] = i0 | ((unsigned int)i1 << 16);
    }
}

// ---------------------------------------------------------------------------
// Inverse: out[bh][l][o] = sum_{m2} UL[l][m2] * V[m2][o]
// grid (BHc, 16), 256 thr. Wave w owns l rows [64w, 64w+64) of a 256-l block.
// Vt staged in LDS [o][136] (17-bank stride).
// ---------------------------------------------------------------------------
__global__ __launch_bounds__(256) void inv_k(const _Float16* __restrict__ UL,
                                             const _Float16* __restrict__ Vt,
                                             float* __restrict__ out) {
    __shared__ _Float16 vs[64 * 136];          // 17.4KB
    int bh = blockIdx.x, lb = blockIdx.y;
    int tid = threadIdx.x, lane = tid & 63, w = tid >> 6;
    int lo16 = lane & 15, kg = lane >> 4;
    #pragma unroll
    for (int i = 0; i < 4; ++i) {
        int f = i * 256 + tid;                 // 1024 chunks of 8 f16
        int row = f >> 4, seg = f & 15;
        uint4 t4 = *(const uint4*)(Vt + (size_t)bh * 8192 + row * 128 + seg * 8);
        *(uint4*)&vs[row * 136 + seg * 8] = t4;
    }
    __syncthreads();
    int lt0 = lb * 256 + w * 64;
    const _Float16* up = UL + (size_t)(lt0 + lo16) * 128 + kg * 8;
    f32x4 acc[4][4] = {};
    #pragma unroll
    for (int ks = 0; ks < 4; ++ks) {
        half8 Af[4];
        #pragma unroll
        for (int a = 0; a < 4; ++a)
            Af[a] = *(const half8*)(up + (size_t)a * 16 * 128 + ks * 32);
        #pragma unroll
        for (int j = 0; j < 4; ++j) {
            half8 Bf = *(const half8*)&vs[(16 * j + lo16) * 136 + ks * 32 + kg * 8];
            #pragma unroll
            for (int a = 0; a < 4; ++a)
                acc[a][j] = __builtin_amdgcn_mfma_f32_16x16x32_f16(Af[a], Bf, acc[a][j], 0, 0, 0);
        }
    }
    float* op = out + ((size_t)bh * Lc + lt0) * Ec;
    #pragma unroll
    for (int a = 0; a < 4; ++a)
        #pragma unroll
        for (int j = 0; j < 4; ++j)
            #pragma unroll
            for (int r = 0; r < 4; ++r) {
                int ll = a * 16 + kg * 4 + r;
                int o  = 16 * j + lo16;
                op[ll * Ec + o] = acc[a][j][r];
            }
}

// ---------------------------------------------------------------------------
extern "C" void kernel_launch(void* const* d_in, const int* in_sizes, int n_in,
                              void* d_out, int out_size, void* d_ws, size_t ws_size,
                              hipStream_t stream) {
    const float* x   = (const float*)d_in[0];
    const float* wgt = (const float*)d_in[1];
    const int*   idx = (const int*)d_in[2];
    float* out = (float*)d_out;

    // workspace layout: selP (nch*4MB) | Tt (1MB) | UL (1MB) | Vt (2MB)
    size_t need8 = (size_t)8 * BHc * 8192 * 4 + (2ull * 128 * Lc + (size_t)BHc * 8192) * 2;
    int nch = (ws_size >= need8) ? 8 : 4;

    char* ws = (char*)d_ws;
    float*    selP = (float*)ws;
    _Float16* Tt   = (_Float16*)(ws + (size_t)nch * BHc * 8192 * 4);
    _Float16* UL   = Tt + (size_t)128 * Lc;
    _Float16* Vt   = UL + (size_t)Lc * 128;

    twid_k<<<2048, 256, 0, stream>>>(idx, Tt, UL);
    if (nch == 8)
        fwd_k<8><<<dim3(BHc, 8), 256, 0, stream>>>(x, Tt, selP);
    else
        fwd_k<4><<<dim3(BHc, 4), 256, 0, stream>>>(x, Tt, selP);
    mix_k<<<dim3(BHc, 2), 256, 0, stream>>>(selP, wgt, idx, Vt, nch);
    inv_k<<<dim3(BHc, 16), 256, 0, stream>>>(UL, Vt, out);
}